// Round 1
// 892.869 us; speedup vs baseline: 1.1247x; 1.1247x over previous
//
#include <hip/hip_runtime.h>
#include <hip/hip_bf16.h>

// Problem constants (B, D, DOUT from reference)
#define BDIM 8192
#define DDIM 4096
#define DOUTD 4096

typedef __attribute__((ext_vector_type(8))) short short8;
typedef __attribute__((ext_vector_type(16))) float floatx16;

// round-to-nearest-even fp32 -> bf16 (bit pattern)
__device__ inline unsigned short f32_to_bf16_rne(float f) {
    unsigned int u = __float_as_uint(f);
    unsigned int lsb = (u >> 16) & 1u;
    u += 0x7fffu + lsb;
    return (unsigned short)(u >> 16);
}

// async global->LDS, 16B per lane; lds base must be wave-uniform
__device__ inline void gload_lds16(const void* g, void* lds) {
    __builtin_amdgcn_global_load_lds(
        (const __attribute__((address_space(1))) void*)g,
        (__attribute__((address_space(3))) void*)lds,
        16, 0, 0);
}

// Convert x (fp32 [B,D]) to bf16 natural (xb [B,D]) and transposed (xT [D,B]).
__global__ __launch_bounds__(256)
void convert_transpose_x(const float* __restrict__ x,
                         unsigned short* __restrict__ xb,
                         unsigned short* __restrict__ xT) {
    __shared__ __align__(16) unsigned short tile[64][72];  // [d][b], +8 pad
    const int t = threadIdx.x;
    const int tb = blockIdx.x * 64;   // b offset
    const int td = blockIdx.y * 64;   // d offset
#pragma unroll
    for (int p = 0; p < 4; ++p) {
        int c = t + p * 256;            // [0,1024)
        int row  = c >> 4;              // b-local
        int col4 = (c & 15) << 2;       // d-local
        float4 v = *(const float4*)&x[(size_t)(tb + row) * DDIM + td + col4];
        ushort4 o;
        o.x = f32_to_bf16_rne(v.x);
        o.y = f32_to_bf16_rne(v.y);
        o.z = f32_to_bf16_rne(v.z);
        o.w = f32_to_bf16_rne(v.w);
        *(ushort4*)&xb[(size_t)(tb + row) * DDIM + td + col4] = o;
        tile[col4 + 0][row] = o.x;
        tile[col4 + 1][row] = o.y;
        tile[col4 + 2][row] = o.z;
        tile[col4 + 3][row] = o.w;
    }
    __syncthreads();
#pragma unroll
    for (int p = 0; p < 4; ++p) {
        int c = t + p * 256;
        int drow = c >> 4;              // d-local
        int b4   = (c & 15) << 2;       // b-local
        ushort4 o = *(const ushort4*)&tile[drow][b4];
        *(ushort4*)&xT[(size_t)(td + drow) * BDIM + tb + b4] = o;
    }
}

// Elementwise fp32 -> bf16 for W
__global__ __launch_bounds__(256)
void convert_w_kernel(const float* __restrict__ W, unsigned short* __restrict__ Wb) {
    size_t i = ((size_t)blockIdx.x * 256 + threadIdx.x) * 4;
    float4 v = *(const float4*)&W[i];
    ushort4 o;
    o.x = f32_to_bf16_rne(v.x);
    o.y = f32_to_bf16_rne(v.y);
    o.z = f32_to_bf16_rne(v.z);
    o.w = f32_to_bf16_rne(v.w);
    *(ushort4*)&Wb[i] = o;
}

// compiler memory fence (zero instructions) + raw barrier: keeps phase
// discipline without __syncthreads()'s vmcnt(0) drain.
#define CFENCE() asm volatile("" ::: "memory")
#define BAR() do { CFENCE(); __builtin_amdgcn_s_barrier(); CFENCE(); } while (0)
#define MFMA_BF16 __builtin_amdgcn_mfma_f32_32x32x16_bf16

// ---------------------------------------------------------------------------
// C[m,n] = sum_k A[m,k]*B[n,k]  (+ bias[n]  or  + eps on diagonal)
// A: [M,K] bf16 row-major, B: [N,K] bf16 row-major, C: [M,N] fp32.
//
// 256x256 tile, BK=64, 512 threads = 8 waves (2M x 4N), wave tile 128x64.
// 8-phase schedule (2 barriers/phase, 4 phases/K-tile), LDS double-buffered
// (128 KiB), counted vmcnt(6) once per K-tile (never 0 in steady state).
//
// LDS layout per operand: [buf(2)][row(256)][kchunk(8)] of 16B chunks with
// 3-bit XOR swizzle: stored chunk pos = kc ^ ((row>>2)&7). Staging keeps the
// global_load_lds destination LINEAR (wave w covers bytes [w*2048,+2048) of a
// 16KB half-tile) and applies the INVERSE swizzle to the per-lane global
// source address. Frag reads (row = 32-aligned base + lm) use key = lm>>2,
// spreading the 64 lanes uniformly over all 8 bank windows (conflict-free).
//
// Stage stream order per K-tile: {Bh0, Ah0, Ah1, Bh1}; issued 7 half-tiles
// ahead. During tile j: P1 issues Bh1(j+1) [other buf]; P2/P3/P4 issue
// Bh0/Ah0/Ah1(j+2) [current buf, each after the last read of that region].
// ---------------------------------------------------------------------------
template <bool HESS>
__global__ __launch_bounds__(512, 2)
void gemm256(const unsigned short* __restrict__ A,
             const unsigned short* __restrict__ B,
             const float* __restrict__ bias,
             float* __restrict__ C,
             int M, int N, int K) {
    __shared__ __align__(16) unsigned short As[32768];  // 2 bufs x 256 x 64
    __shared__ __align__(16) unsigned short Bs[32768];

    const int t    = threadIdx.x;
    const int lane = t & 63;
    const int w    = t >> 6;          // wave 0..7
    const int lm   = lane & 31;
    const int hi   = lane >> 5;       // k-half within MFMA operand
    const int key  = lm >> 2;         // read-side swizzle key (rows 32-aligned)
    const int wm   = w >> 2;          // 0..1  (M half of block tile)
    const int wn   = w & 3;           // 0..3  (N quarter)
    const size_t bm = (size_t)blockIdx.y * 256;
    const size_t bn = (size_t)blockIdx.x * 256;
    const int NT = K >> 6;            // K-tiles (>= 2 for our shapes)

    // ---- staging source pointers (per lane), inverse-swizzled k chunk ----
    const int r8  = lane >> 3;        // row within 8-row group
    const int c8  = lane & 7;         // stored chunk position
    const int rl0 = w * 16 + r8;      // g=0 row within 128-row half
    const int rl1 = rl0 + 8;          // g=1
    const int kc0 = c8 ^ ((w * 4 + (lane >> 5)) & 7);
    const int kc1 = c8 ^ ((w * 4 + 2 + (lane >> 5)) & 7);
    const unsigned short* gA0 = A + (bm + rl0) * (size_t)K + kc0 * 8;
    const unsigned short* gA1 = A + (bm + rl1) * (size_t)K + kc1 * 8;
    const unsigned short* gB0 = B + (bn + rl0) * (size_t)K + kc0 * 8;
    const unsigned short* gB1 = B + (bn + rl1) * (size_t)K + kc1 * 8;
    char* ldsA = (char*)As + w * 2048;   // wave-linear dest within half-tile
    char* ldsB = (char*)Bs + w * 2048;
    const size_t halfK = (size_t)128 * K;   // shorts: half-tile row jump

#define STAGE_A(tj, h, buf) do {                                   \
        const size_t _ko = (size_t)(tj) * 64 + (size_t)(h) * halfK;\
        char* _d = ldsA + (buf) * 32768 + (h) * 16384;             \
        gload_lds16(gA0 + _ko, _d);                                \
        gload_lds16(gA1 + _ko, _d + 1024);                         \
    } while (0)
#define STAGE_B(tj, h, buf) do {                                   \
        const size_t _ko = (size_t)(tj) * 64 + (size_t)(h) * halfK;\
        char* _d = ldsB + (buf) * 32768 + (h) * 16384;             \
        gload_lds16(gB0 + _ko, _d);                                \
        gload_lds16(gB1 + _ko, _d + 1024);                         \
    } while (0)

    // ---- read offsets (shorts) ----
    const int AROW = (wm * 128 + lm) * 64;   // + qm*4096 + mi*2048
    const int BROW = (wn * 32 + lm) * 64;    // + qn*8192
    int swz[4];
#pragma unroll
    for (int s = 0; s < 4; ++s) swz[s] = (((2 * s + hi) ^ key) << 3);

    floatx16 acc[4][2];   // [qm*2+mi][qn]
#pragma unroll
    for (int i = 0; i < 4; ++i)
#pragma unroll
        for (int j = 0; j < 2; ++j)
#pragma unroll
            for (int g = 0; g < 16; ++g)
                acc[i][j][g] = 0.f;

    short8 af0[2][4], af1[2][4], bf[4];

    // ---- prologue: 7 half-tiles ahead, then wait tile0 landed ----
    STAGE_B(0, 0, 0);
    STAGE_A(0, 0, 0);
    STAGE_A(0, 1, 0);
    STAGE_B(0, 1, 0);
    STAGE_B(1, 0, 1);
    STAGE_A(1, 0, 1);
    STAGE_A(1, 1, 1);
    asm volatile("s_waitcnt vmcnt(6)" ::: "memory");
    BAR();

    for (int j = 0; j < NT; ++j) {
        const int cur = j & 1;
        const int ab  = cur * 16384;   // shorts

        // ---------- P1: read af0 (qm=0) + bf (qn=0); stage Bh1(j+1) ----------
#pragma unroll
        for (int mi = 0; mi < 2; ++mi)
#pragma unroll
            for (int s = 0; s < 4; ++s)
                af0[mi][s] = *(const short8*)&As[ab + AROW + mi * 2048 + swz[s]];
#pragma unroll
        for (int s = 0; s < 4; ++s)
            bf[s] = *(const short8*)&Bs[ab + BROW + swz[s]];
        if (j + 1 < NT) STAGE_B(j + 1, 1, cur ^ 1);
        BAR();
        __builtin_amdgcn_s_setprio(1);
#pragma unroll
        for (int s = 0; s < 4; ++s) {
            acc[0][0] = MFMA_BF16(af0[0][s], bf[s], acc[0][0], 0, 0, 0);
            acc[1][0] = MFMA_BF16(af0[1][s], bf[s], acc[1][0], 0, 0, 0);
        }
        __builtin_amdgcn_s_setprio(0);
        asm volatile("s_waitcnt lgkmcnt(0)" ::: "memory");
        BAR();

        // ---------- P2: read af1 (qm=1); stage Bh0(j+2) ----------
#pragma unroll
        for (int mi = 0; mi < 2; ++mi)
#pragma unroll
            for (int s = 0; s < 4; ++s)
                af1[mi][s] = *(const short8*)&As[ab + AROW + 4096 + mi * 2048 + swz[s]];
        if (j + 2 < NT) STAGE_B(j + 2, 0, cur);
        BAR();
        __builtin_amdgcn_s_setprio(1);
#pragma unroll
        for (int s = 0; s < 4; ++s) {
            acc[2][0] = MFMA_BF16(af1[0][s], bf[s], acc[2][0], 0, 0, 0);
            acc[3][0] = MFMA_BF16(af1[1][s], bf[s], acc[3][0], 0, 0, 0);
        }
        __builtin_amdgcn_s_setprio(0);
        asm volatile("s_waitcnt lgkmcnt(0)" ::: "memory");
        BAR();

        // ---------- P3: read bf (qn=1); stage Ah0(j+2) ----------
#pragma unroll
        for (int s = 0; s < 4; ++s)
            bf[s] = *(const short8*)&Bs[ab + BROW + 8192 + swz[s]];
        if (j + 2 < NT) STAGE_A(j + 2, 0, cur);
        BAR();
        __builtin_amdgcn_s_setprio(1);
#pragma unroll
        for (int s = 0; s < 4; ++s) {
            acc[2][1] = MFMA_BF16(af1[0][s], bf[s], acc[2][1], 0, 0, 0);
            acc[3][1] = MFMA_BF16(af1[1][s], bf[s], acc[3][1], 0, 0, 0);
        }
        __builtin_amdgcn_s_setprio(0);
        asm volatile("s_waitcnt lgkmcnt(0)" ::: "memory");
        BAR();

        // ---------- P4: stage Ah1(j+2); MFMA Q(0,1); counted vmcnt ----------
        if (j + 2 < NT) STAGE_A(j + 2, 1, cur);
        BAR();
        __builtin_amdgcn_s_setprio(1);
#pragma unroll
        for (int s = 0; s < 4; ++s) {
            acc[0][1] = MFMA_BF16(af0[0][s], bf[s], acc[0][1], 0, 0, 0);
            acc[1][1] = MFMA_BF16(af0[1][s], bf[s], acc[1][1], 0, 0, 0);
        }
        __builtin_amdgcn_s_setprio(0);
        if (j < NT - 2)       asm volatile("s_waitcnt vmcnt(6)" ::: "memory");
        else if (j == NT - 2) asm volatile("s_waitcnt vmcnt(0)" ::: "memory");
        BAR();
    }
#undef STAGE_A
#undef STAGE_B

    // ---- epilogue: D layout col = lane&31 (n), row = (reg&3)+8*(reg>>2)+4*hi
    float bv[2];
#pragma unroll
    for (int n2 = 0; n2 < 2; ++n2)
        bv[n2] = HESS ? 0.f : bias[bn + n2 * 128 + wn * 32 + lm];
#pragma unroll
    for (int m4 = 0; m4 < 4; ++m4) {
        const size_t mbase = bm + wm * 128 + (m4 >> 1) * 64 + (m4 & 1) * 32 + 4 * hi;
#pragma unroll
        for (int n2 = 0; n2 < 2; ++n2) {
            const size_t n = bn + n2 * 128 + wn * 32 + lm;
#pragma unroll
            for (int reg = 0; reg < 16; ++reg) {
                const size_t m = mbase + (reg & 3) + 8 * (reg >> 2);
                float v = acc[m4][n2][reg] + bv[n2];
                if (HESS && m == n) v += 1e-4f;
                C[m * N + n] = v;
            }
        }
    }
}

extern "C" void kernel_launch(void* const* d_in, const int* in_sizes, int n_in,
                              void* d_out, int out_size, void* d_ws, size_t ws_size,
                              hipStream_t stream) {
    const float* x = (const float*)d_in[0];   // [8192, 4096]
    const float* W = (const float*)d_in[1];   // [4096, 4096]
    const float* b = (const float*)d_in[2];   // [4096]

    float* out  = (float*)d_out;                       // [8192, 4096]
    float* hess = out + (size_t)BDIM * DOUTD;          // [4096, 4096]

    // workspace layout (bf16): xb [B,D] | xT [D,B] | Wb [DOUT,D]  = 168 MB
    unsigned short* xb = (unsigned short*)d_ws;
    unsigned short* xT = xb + (size_t)BDIM * DDIM;
    unsigned short* Wb = xT + (size_t)BDIM * DDIM;

    convert_transpose_x<<<dim3(BDIM / 64, DDIM / 64), 256, 0, stream>>>(x, xb, xT);
    convert_w_kernel<<<((size_t)DOUTD * DDIM) / 1024, 256, 0, stream>>>(W, Wb);

    // out = x @ W.T + b : M=8192, N=4096, K=4096  (grid 16 x 32 = 512 blocks)
    gemm256<false><<<dim3(DOUTD / 256, BDIM / 256), 512, 0, stream>>>(
        xb, Wb, b, out, BDIM, DOUTD, DDIM);
    // hess = xT @ xT.T + eps*I : M=N=4096, K=8192  (grid 16 x 16 = 256 blocks)
    gemm256<true><<<dim3(DDIM / 256, DDIM / 256), 512, 0, stream>>>(
        xT, xT, nullptr, hess, DDIM, DDIM, BDIM);
}

// Round 2
// 858.664 us; speedup vs baseline: 1.1695x; 1.0398x over previous
//
#include <hip/hip_runtime.h>
#include <hip/hip_bf16.h>

// Problem constants (B, D, DOUT from reference)
#define BDIM 8192
#define DDIM 4096
#define DOUTD 4096

typedef __attribute__((ext_vector_type(8))) short short8;
typedef __attribute__((ext_vector_type(16))) float floatx16;

// round-to-nearest-even fp32 -> bf16 (bit pattern)
__device__ inline unsigned short f32_to_bf16_rne(float f) {
    unsigned int u = __float_as_uint(f);
    unsigned int lsb = (u >> 16) & 1u;
    u += 0x7fffu + lsb;
    return (unsigned short)(u >> 16);
}

// async global->LDS, 16B per lane; lds base must be wave-uniform
__device__ inline void gload_lds16(const void* g, void* lds) {
    __builtin_amdgcn_global_load_lds(
        (const __attribute__((address_space(1))) void*)g,
        (__attribute__((address_space(3))) void*)lds,
        16, 0, 0);
}

// Convert x (fp32 [B,D]) to bf16 natural (xb [B,D]) and transposed (xT [D,B]).
__global__ __launch_bounds__(256)
void convert_transpose_x(const float* __restrict__ x,
                         unsigned short* __restrict__ xb,
                         unsigned short* __restrict__ xT) {
    __shared__ __align__(16) unsigned short tile[64][72];  // [d][b], +8 pad
    const int t = threadIdx.x;
    const int tb = blockIdx.x * 64;   // b offset
    const int td = blockIdx.y * 64;   // d offset
#pragma unroll
    for (int p = 0; p < 4; ++p) {
        int c = t + p * 256;            // [0,1024)
        int row  = c >> 4;              // b-local
        int col4 = (c & 15) << 2;       // d-local
        float4 v = *(const float4*)&x[(size_t)(tb + row) * DDIM + td + col4];
        ushort4 o;
        o.x = f32_to_bf16_rne(v.x);
        o.y = f32_to_bf16_rne(v.y);
        o.z = f32_to_bf16_rne(v.z);
        o.w = f32_to_bf16_rne(v.w);
        *(ushort4*)&xb[(size_t)(tb + row) * DDIM + td + col4] = o;
        tile[col4 + 0][row] = o.x;
        tile[col4 + 1][row] = o.y;
        tile[col4 + 2][row] = o.z;
        tile[col4 + 3][row] = o.w;
    }
    __syncthreads();
#pragma unroll
    for (int p = 0; p < 4; ++p) {
        int c = t + p * 256;
        int drow = c >> 4;              // d-local
        int b4   = (c & 15) << 2;       // b-local
        ushort4 o = *(const ushort4*)&tile[drow][b4];
        *(ushort4*)&xT[(size_t)(td + drow) * BDIM + tb + b4] = o;
    }
}

// Elementwise fp32 -> bf16 for W
__global__ __launch_bounds__(256)
void convert_w_kernel(const float* __restrict__ W, unsigned short* __restrict__ Wb) {
    size_t i = ((size_t)blockIdx.x * 256 + threadIdx.x) * 4;
    float4 v = *(const float4*)&W[i];
    ushort4 o;
    o.x = f32_to_bf16_rne(v.x);
    o.y = f32_to_bf16_rne(v.y);
    o.z = f32_to_bf16_rne(v.z);
    o.w = f32_to_bf16_rne(v.w);
    *(ushort4*)&Wb[i] = o;
}

// compiler memory fence (zero instructions) + raw barrier: keeps phase
// discipline without __syncthreads()'s vmcnt(0) drain.
#define CFENCE() asm volatile("" ::: "memory")
#define BAR() do { CFENCE(); __builtin_amdgcn_s_barrier(); CFENCE(); } while (0)
#define MFMA_BF16 __builtin_amdgcn_mfma_f32_32x32x16_bf16

// ---------------------------------------------------------------------------
// C[m,n] = sum_k A[m,k]*B[n,k]  (+ bias[n]  or  + eps on diagonal)
// A: [M,K] bf16 row-major, B: [N,K] bf16 row-major, C: [M,N] fp32.
//
// 256x256 tile, BK=64, 512 threads = 8 waves (2M x 4N), wave tile 128x64.
// 8-phase schedule (2 barriers/phase, 4 phases/K-tile), LDS double-buffered
// (128 KiB), counted vmcnt(6) once per K-tile (never 0 in steady state).
//
// LDS layout (v2, bank-conflict fix): per operand per buffer (32KB):
//   [kh(2) x 16KB regions][row(256) x 64B][p(4) x 16B chunks]
// i.e. the 64-element K-row is SPLIT into two 64B sub-rows (kh = kchunk>>2)
// stored in separate regions. Each region uses the empirically zero-conflict
// BK=32 scheme: stored chunk pos p = c2 ^ ((row>>2)&3). With a 64B row
// stride, bank = (row&1)*16 + p*4 + d  -- row parity contributes a bank bit,
// which the flat 128B-stride layout lost (that cost 2.5e7 conflicts/dispatch,
// ~4 extra cyc per ds_read_b128).
// Staging keeps global_load_lds dests LINEAR: wave w covers region kh=w>>2,
// 2KB stripe (w&3) of each 8KB (half-tile x region) block; the per-lane
// GLOBAL source k-chunk carries the inverse swizzle csrc = (lane&3)^((lane>>4)&3).
//
// Frag read for MFMA slice s stays within one region: kh = s>>1,
// c2 = (s&1)*2 + hi, p = c2 ^ ((lm>>2)&3) (row bases 32-aligned).
//
// Stage stream order per K-tile: {Bh0, Ah0, Ah1, Bh1}; issued 7 half-tiles
// ahead. During tile j: P1 issues Bh1(j+1) [other buf]; P2/P3/P4 issue
// Bh0/Ah0/Ah1(j+2) [current buf, each after the last read of that region].
// ---------------------------------------------------------------------------
template <bool HESS>
__global__ __launch_bounds__(512, 2)
void gemm256(const unsigned short* __restrict__ A,
             const unsigned short* __restrict__ B,
             const float* __restrict__ bias,
             float* __restrict__ C,
             int M, int N, int K) {
    __shared__ __align__(16) unsigned short As[32768];  // 2 buf x 2 region x 256 x 32
    __shared__ __align__(16) unsigned short Bs[32768];

    const int t    = threadIdx.x;
    const int lane = t & 63;
    const int w    = t >> 6;          // wave 0..7
    const int lm   = lane & 31;
    const int hi   = lane >> 5;       // k-half within MFMA operand
    const int key2 = (lm >> 2) & 3;   // read-side swizzle key (rows 32-aligned)
    const int wm   = w >> 2;          // 0..1  (M half of block tile)
    const int wn   = w & 3;           // 0..3  (N quarter)
    const size_t bm = (size_t)blockIdx.y * 256;
    const size_t bn = (size_t)blockIdx.x * 256;
    const int NT = K >> 6;            // K-tiles (>= 2 for our shapes)

    // ---- staging (per lane), inverse-swizzled source k-chunk ----
    const int kh_w = w >> 2;          // which 64B k-half this wave stages
    const int wq   = w & 3;           // 2KB stripe within (half-tile, region)
    const int rsub = lane >> 2;       // row within 16-row stripe
    const int csrc = (lane & 3) ^ ((lane >> 4) & 3);  // global k-chunk (of 4)
    const unsigned short* gA0 = A + (bm + wq * 32 + rsub) * (size_t)K + kh_w * 32 + csrc * 8;
    const unsigned short* gB0 = B + (bn + wq * 32 + rsub) * (size_t)K + kh_w * 32 + csrc * 8;
    char* ldsA = (char*)As + kh_w * 16384 + wq * 2048;  // + buf*32768 + h*8192
    char* ldsB = (char*)Bs + kh_w * 16384 + wq * 2048;
    const size_t rowK16 = (size_t)16 * K;   // 16 rows (shorts)
    const size_t halfK  = (size_t)128 * K;  // half-tile row jump (shorts)

#define STAGE_A(tj, h, buf) do {                                   \
        const size_t _ko = (size_t)(tj) * 64 + (size_t)(h) * halfK;\
        char* _d = ldsA + (buf) * 32768 + (h) * 8192;              \
        gload_lds16(gA0 + _ko, _d);                                \
        gload_lds16(gA0 + _ko + rowK16, _d + 1024);                \
    } while (0)
#define STAGE_B(tj, h, buf) do {                                   \
        const size_t _ko = (size_t)(tj) * 64 + (size_t)(h) * halfK;\
        char* _d = ldsB + (buf) * 32768 + (h) * 8192;              \
        gload_lds16(gB0 + _ko, _d);                                \
        gload_lds16(gB0 + _ko + rowK16, _d + 1024);                \
    } while (0)

    // ---- read offsets (shorts): addr = ab + ROWb + quad-offset + pofs[s] ----
    const int AROWb = (wm * 128 + lm) * 32;  // + qm*2048 + mi*1024
    const int BROWb = (wn * 32 + lm) * 32;   // + qn*4096
    int pofs[4];
#pragma unroll
    for (int s = 0; s < 4; ++s)
        pofs[s] = (s >> 1) * 8192 + ((((s & 1) * 2 + hi) ^ key2) * 8);

    floatx16 acc[4][2];   // [qm*2+mi][qn]
#pragma unroll
    for (int i = 0; i < 4; ++i)
#pragma unroll
        for (int j = 0; j < 2; ++j)
#pragma unroll
            for (int g = 0; g < 16; ++g)
                acc[i][j][g] = 0.f;

    short8 af0[2][4], af1[2][4], bf[4];

    // ---- prologue: 7 half-tiles ahead, then wait tile0 landed ----
    STAGE_B(0, 0, 0);
    STAGE_A(0, 0, 0);
    STAGE_A(0, 1, 0);
    STAGE_B(0, 1, 0);
    STAGE_B(1, 0, 1);
    STAGE_A(1, 0, 1);
    STAGE_A(1, 1, 1);
    asm volatile("s_waitcnt vmcnt(6)" ::: "memory");
    BAR();

    for (int j = 0; j < NT; ++j) {
        const int cur = j & 1;
        const int ab  = cur * 16384;   // shorts

        // ---------- P1: read af0 (qm=0) + bf (qn=0); stage Bh1(j+1) ----------
#pragma unroll
        for (int mi = 0; mi < 2; ++mi)
#pragma unroll
            for (int s = 0; s < 4; ++s)
                af0[mi][s] = *(const short8*)&As[ab + AROWb + mi * 1024 + pofs[s]];
#pragma unroll
        for (int s = 0; s < 4; ++s)
            bf[s] = *(const short8*)&Bs[ab + BROWb + pofs[s]];
        if (j + 1 < NT) STAGE_B(j + 1, 1, cur ^ 1);
        BAR();
        __builtin_amdgcn_s_setprio(1);
#pragma unroll
        for (int s = 0; s < 4; ++s) {
            acc[0][0] = MFMA_BF16(af0[0][s], bf[s], acc[0][0], 0, 0, 0);
            acc[1][0] = MFMA_BF16(af0[1][s], bf[s], acc[1][0], 0, 0, 0);
        }
        __builtin_amdgcn_s_setprio(0);
        asm volatile("s_waitcnt lgkmcnt(0)" ::: "memory");
        BAR();

        // ---------- P2: read af1 (qm=1); stage Bh0(j+2) ----------
#pragma unroll
        for (int mi = 0; mi < 2; ++mi)
#pragma unroll
            for (int s = 0; s < 4; ++s)
                af1[mi][s] = *(const short8*)&As[ab + AROWb + 2048 + mi * 1024 + pofs[s]];
        if (j + 2 < NT) STAGE_B(j + 2, 0, cur);
        BAR();
        __builtin_amdgcn_s_setprio(1);
#pragma unroll
        for (int s = 0; s < 4; ++s) {
            acc[2][0] = MFMA_BF16(af1[0][s], bf[s], acc[2][0], 0, 0, 0);
            acc[3][0] = MFMA_BF16(af1[1][s], bf[s], acc[3][0], 0, 0, 0);
        }
        __builtin_amdgcn_s_setprio(0);
        asm volatile("s_waitcnt lgkmcnt(0)" ::: "memory");
        BAR();

        // ---------- P3: read bf (qn=1); stage Ah0(j+2) ----------
#pragma unroll
        for (int s = 0; s < 4; ++s)
            bf[s] = *(const short8*)&Bs[ab + BROWb + 4096 + pofs[s]];
        if (j + 2 < NT) STAGE_A(j + 2, 0, cur);
        BAR();
        __builtin_amdgcn_s_setprio(1);
#pragma unroll
        for (int s = 0; s < 4; ++s) {
            acc[2][1] = MFMA_BF16(af1[0][s], bf[s], acc[2][1], 0, 0, 0);
            acc[3][1] = MFMA_BF16(af1[1][s], bf[s], acc[3][1], 0, 0, 0);
        }
        __builtin_amdgcn_s_setprio(0);
        asm volatile("s_waitcnt lgkmcnt(0)" ::: "memory");
        BAR();

        // ---------- P4: stage Ah1(j+2); MFMA Q(0,1); counted vmcnt ----------
        if (j + 2 < NT) STAGE_A(j + 2, 1, cur);
        BAR();
        __builtin_amdgcn_s_setprio(1);
#pragma unroll
        for (int s = 0; s < 4; ++s) {
            acc[0][1] = MFMA_BF16(af0[0][s], bf[s], acc[0][1], 0, 0, 0);
            acc[1][1] = MFMA_BF16(af0[1][s], bf[s], acc[1][1], 0, 0, 0);
        }
        __builtin_amdgcn_s_setprio(0);
        if (j < NT - 2)       asm volatile("s_waitcnt vmcnt(6)" ::: "memory");
        else if (j == NT - 2) asm volatile("s_waitcnt vmcnt(0)" ::: "memory");
        BAR();
    }
#undef STAGE_A
#undef STAGE_B

    // ---- epilogue: D layout col = lane&31 (n), row = (reg&3)+8*(reg>>2)+4*hi
    float bv[2];
#pragma unroll
    for (int n2 = 0; n2 < 2; ++n2)
        bv[n2] = HESS ? 0.f : bias[bn + n2 * 128 + wn * 32 + lm];
#pragma unroll
    for (int m4 = 0; m4 < 4; ++m4) {
        const size_t mbase = bm + wm * 128 + (m4 >> 1) * 64 + (m4 & 1) * 32 + 4 * hi;
#pragma unroll
        for (int n2 = 0; n2 < 2; ++n2) {
            const size_t n = bn + n2 * 128 + wn * 32 + lm;
#pragma unroll
            for (int reg = 0; reg < 16; ++reg) {
                const size_t m = mbase + (reg & 3) + 8 * (reg >> 2);
                float v = acc[m4][n2][reg] + bv[n2];
                if (HESS && m == n) v += 1e-4f;
                C[m * N + n] = v;
            }
        }
    }
}

extern "C" void kernel_launch(void* const* d_in, const int* in_sizes, int n_in,
                              void* d_out, int out_size, void* d_ws, size_t ws_size,
                              hipStream_t stream) {
    const float* x = (const float*)d_in[0];   // [8192, 4096]
    const float* W = (const float*)d_in[1];   // [4096, 4096]
    const float* b = (const float*)d_in[2];   // [4096]

    float* out  = (float*)d_out;                       // [8192, 4096]
    float* hess = out + (size_t)BDIM * DOUTD;          // [4096, 4096]

    // workspace layout (bf16): xb [B,D] | xT [D,B] | Wb [DOUT,D]  = 168 MB
    unsigned short* xb = (unsigned short*)d_ws;
    unsigned short* xT = xb + (size_t)BDIM * DDIM;
    unsigned short* Wb = xT + (size_t)BDIM * DDIM;

    convert_transpose_x<<<dim3(BDIM / 64, DDIM / 64), 256, 0, stream>>>(x, xb, xT);
    convert_w_kernel<<<((size_t)DOUTD * DDIM) / 1024, 256, 0, stream>>>(W, Wb);

    // out = x @ W.T + b : M=8192, N=4096, K=4096  (grid 16 x 32 = 512 blocks)
    gemm256<false><<<dim3(DOUTD / 256, BDIM / 256), 512, 0, stream>>>(
        xb, Wb, b, out, BDIM, DOUTD, DDIM);
    // hess = xT @ xT.T + eps*I : M=N=4096, K=8192  (grid 16 x 16 = 256 blocks)
    gemm256<true><<<dim3(DDIM / 256, DDIM / 256), 512, 0, stream>>>(
        xT, xT, nullptr, hess, DDIM, DDIM, BDIM);
}